// Round 2
// baseline (4554.161 us; speedup 1.0000x reference)
//
#include <hip/hip_runtime.h>
#include <stdint.h>

// Conductance-LIF network, persistent event-driven kernel. Round 2.
//
// Key changes vs round 1:
//  * blockIdx mapping INVERTED: j = blockIdx&7 (column slice), b = blockIdx>>3.
//    Under round-robin blockIdx%8 -> XCD dispatch, all 32 blocks sharing a
//    column slice land on one XCD, so that slice of W (1.18 MB) + WF (0.59 MB)
//    stays L2-resident and every gather load is an L2 hit. (Mapping is a perf
//    heuristic only — correctness never depends on placement.)
//  * float4 gather with 16-way K-split (768 threads = 48 col-groups x 16):
//    4x fewer load instructions, 16 B per load, unroll 4 for MLP.
//  * Nontemporal output stores + input loads: no RFO fetch, no L2 pollution
//    (protects the resident W slice).
//
// Spikes are binary -> matmuls are row-sums over the spiking set. Synapses 0,1
// share the ct0 pre-mask => two recurrent sums (z0,z1) + one FF sum; scaling
// factors are (pre-ct,post-ct) separable => applied post-sum.
//
// Cross-block (same-batch) spike exchange: write-once recmask/recflag in d_ws,
// agent-scope atomics (per-XCD L2s not coherent). MAGIC != 0xAAAAAAAA poison.
// All 256 blocks co-resident (3072 waves << 8192 slots) => spin is safe.

#define MAGIC 0x5EED5EEDu

__global__ __launch_bounds__(768) void snn_lif_kernel(
    const float* __restrict__ I,     // [32][256][768] input spikes (0/1)
    const float* __restrict__ W,     // [1536][1536] recurrent weights (row = pre)
    const float* __restrict__ WF,    // [768][1536]  FF weights (row = input)
    const float* __restrict__ sf,    // [2][2] scaling (pre ct, post ct)
    const float* __restrict__ sfF,   // [1][2] FF scaling (post ct)
    const int*   __restrict__ ct,    // [1536] cell type 0/1
    float* __restrict__ out,         // spk [32][256][1536] then volt [...]
    uint64_t* __restrict__ recmask,  // [32][256][24] spike bit-words
    uint32_t* __restrict__ recflag)  // [32][256][24] publish flags
{
    const int tid = threadIdx.x;
    const int j   = blockIdx.x & 7;    // column-slice id -> XCD under %8 RR
    const int b   = blockIdx.x >> 3;   // batch
    const int wv  = tid >> 6;          // wave 0..11
    const int wl  = tid & 63;          // lane
    const int kk  = tid / 48;          // K-split group 0..15
    const int cg  = tid - kk * 48;     // col-group 0..47 (4 cols each)

    __shared__ uint32_t ent[3840];         // L0:[0,1536) L1:[1536,3072) F:[3072,3840)
    __shared__ float    part[3][16][192];  // per-K-group partial sums
    __shared__ uint32_t totals_sh;
    __shared__ uint64_t ctm_sh[24];        // cell-type bitmask
    __shared__ uint64_t fmask_sh[12];      // this-step FF spike mask

    // ---- cell-type bitmask via block-wide ballots ----
    for (int r = 0; r < 2; ++r) {
        int c = ct[r * 768 + tid];
        uint64_t bal = __ballot(c != 0);
        if (wl == 0) ctm_sh[r * 12 + wv] = bal;
    }
    __syncthreads();

    // ---- owner-neuron constants (threads 0..191 own neuron m) ----
    const int m = j * 192 + ((tid < 192) ? tid : 0);
    const int   myct = ct[m];
    const float s0m  = sf[myct];
    const float s1m  = sf[2 + myct];
    const float sFm  = sfF[myct];
    const float lc   = (myct == 0) ? (1.0f / 200.0f) : (1.0f / 100.0f);
    const float refsteps = (myct == 0) ? 2.0f : 1.0f;
    const float ar0 = expf(-1.0f / 0.5f),  ad0 = expf(-1.0f / 2.0f);
    const float ar1 = expf(-1.0f / 2.0f),  ad1 = expf(-1.0f / 100.0f);
    const float ar2 = expf(-1.0f / 0.5f),  ad2 = expf(-1.0f / 5.0f);
    const float arF = expf(-1.0f / 0.5f),  adF = expf(-1.0f / 2.0f);

    float U = -65.0f, refc = 0.0f;
    float x0 = 0, g0 = 0, x1 = 0, g1 = 0, x2 = 0, g2 = 0, xF = 0, gF = 0;

    const uint64_t ctw = (wl < 24) ? ctm_sh[wl] : 0ull;
    const int btbase = b * 256;
    const uint32_t colv = (uint32_t)(j * 48 + cg);   // float4 index within a row

    for (int t = 0; t < 256; ++t) {
        // ---- FF spike ballot for this step ----
        float iv = __builtin_nontemporal_load(&I[(uint32_t)(btbase + t) * 768u + (uint32_t)tid]);
        uint64_t fb = __ballot(iv > 0.5f);
        if (wl == 0) fmask_sh[wv] = fb;
        __syncthreads();   // (c)

        // ---- phase A (wave 0): poll siblings' spikes, build entry lists ----
        if (wv == 0) {
            uint64_t sm = 0, fm = 0;
            uint32_t c0 = 0, c1 = 0, cF = 0;
            if (wl < 24) {
                if (t > 0) {
                    const uint32_t fi = (uint32_t)(btbase + t - 1) * 24u + (uint32_t)wl;
                    while (__hip_atomic_load(&recflag[fi], __ATOMIC_ACQUIRE,
                                             __HIP_MEMORY_SCOPE_AGENT) != MAGIC) { }
                    sm = __hip_atomic_load(&recmask[fi], __ATOMIC_RELAXED,
                                           __HIP_MEMORY_SCOPE_AGENT);
                }
                c0 = __popcll(sm & ~ctw);
                c1 = __popcll(sm & ctw);
            } else if (wl < 36) {
                fm = fmask_sh[wl - 24];
                cF = __popcll(fm);
            }
            uint32_t pack = c0 | (c1 << 11) | (cF << 22);   // 11/11/10-bit fields
            uint32_t incl = pack;
            #pragma unroll
            for (int d = 1; d < 64; d <<= 1) {
                uint32_t u = __shfl_up(incl, d, 64);
                if (wl >= d) incl += u;
            }
            const uint32_t excl = incl - pack;
            if (wl == 35) totals_sh = incl;
            uint32_t p0 = excl & 0x7FFu;
            uint32_t p1 = 1536u + ((excl >> 11) & 0x7FFu);
            uint32_t pF = 3072u + (excl >> 22);
            if (wl < 24) {
                uint64_t mm = sm;
                const uint32_t lanebase = (uint32_t)wl * 64u * 1536u;
                while (mm) {
                    const int bit = __builtin_ctzll(mm);
                    mm &= mm - 1;
                    const uint32_t off = lanebase + (uint32_t)bit * 1536u;
                    if ((ctw >> bit) & 1ull) ent[p1++] = off;
                    else                     ent[p0++] = off;
                }
            } else if (wl < 36) {
                uint64_t mm = fm;
                const uint32_t lanebase = (uint32_t)(wl - 24) * 64u * 1536u;
                while (mm) {
                    const int bit = __builtin_ctzll(mm);
                    mm &= mm - 1;
                    ent[pF++] = lanebase + (uint32_t)bit * 1536u;
                }
            }
        }
        __syncthreads();   // (b)

        // ---- phase B: float4 gather, 16-way K-split ----
        const uint32_t tp = totals_sh;
        const uint32_t t0 = tp & 0x7FFu;
        const uint32_t t1 = (tp >> 11) & 0x7FFu;
        const uint32_t tF = tp >> 22;
        float4 z0 = make_float4(0.f, 0.f, 0.f, 0.f);
        float4 z1 = z0, zF = z0;
        #pragma unroll 4
        for (uint32_t i = (uint32_t)kk; i < t0; i += 16u) {
            const float4 w = ((const float4*)(W + ent[i]))[colv];
            z0.x += w.x; z0.y += w.y; z0.z += w.z; z0.w += w.w;
        }
        #pragma unroll 4
        for (uint32_t i = (uint32_t)kk; i < t1; i += 16u) {
            const float4 w = ((const float4*)(W + ent[1536u + i]))[colv];
            z1.x += w.x; z1.y += w.y; z1.z += w.z; z1.w += w.w;
        }
        #pragma unroll 4
        for (uint32_t i = (uint32_t)kk; i < tF; i += 16u) {
            const float4 w = ((const float4*)(WF + ent[3072u + i]))[colv];
            zF.x += w.x; zF.y += w.y; zF.z += w.z; zF.w += w.w;
        }
        *(float4*)&part[0][kk][cg * 4] = z0;
        *(float4*)&part[1][kk][cg * 4] = z1;
        *(float4*)&part[2][kk][cg * 4] = zF;
        __syncthreads();   // (a)

        // ---- phase C (threads 0..191): reduce, LIF update, publish ----
        if (tid < 192) {
            float z0s = 0.f, z1s = 0.f, zFs = 0.f;
            #pragma unroll
            for (int k = 0; k < 16; ++k) {
                z0s += part[0][k][tid];
                z1s += part[1][k][tid];
                zFs += part[2][k][tid];
            }
            z0s *= s0m; z1s *= s1m; zFs *= sFm;
            x0 = ar0 * x0 + z0s;  g0 = ad0 * g0 + x0;   // syn0 (pre ct0)
            x1 = ar1 * x1 + z0s;  g1 = ad1 * g1 + x1;   // syn1 (pre ct0, same z0)
            x2 = ar2 * x2 + z1s;  g2 = ad2 * g2 + x2;   // syn2 (pre ct1)
            xF = arF * xF + zFs;  gF = adF * gF + xF;   // feed-forward
            const float gtot = g0 + 0.5f * g1 + g2 + gF;   // gbar=[1,.5,1], FF 1
            const float gE   = -70.0f * g2;                // gbar*Erev=[0,0,-70], FF 0
            const float Isyn = gE - gtot * U;
            float Un = U + lc * (10.0f * (-65.0f - U) + Isyn);
            if (refc > 0.0f) Un = -65.0f;
            refc = fmaxf(refc - 1.0f, 0.0f);
            const bool s = (Un - (-50.0f)) >= 0.0f;
            const float Uo = s ? -65.0f : Un;
            refc = s ? refsteps : refc;
            U = Uo;
            const uint32_t oidx = (uint32_t)(btbase + t) * 1536u + (uint32_t)m;
            __builtin_nontemporal_store(s ? 1.0f : 0.0f, &out[oidx]);
            __builtin_nontemporal_store(Uo, &out[12582912u + oidx]);
            const uint64_t bal = __ballot(s);   // waves 0..2 fully inside tid<192
            if (wl == 0) {
                const uint32_t widx = (uint32_t)(btbase + t) * 24u + (uint32_t)(j * 3 + wv);
                __hip_atomic_store(&recmask[widx], bal, __ATOMIC_RELAXED,
                                   __HIP_MEMORY_SCOPE_AGENT);
                __hip_atomic_store(&recflag[widx], MAGIC, __ATOMIC_RELEASE,
                                   __HIP_MEMORY_SCOPE_AGENT);
            }
        }
    }
}

extern "C" void kernel_launch(void* const* d_in, const int* in_sizes, int n_in,
                              void* d_out, int out_size, void* d_ws, size_t ws_size,
                              hipStream_t stream) {
    const float* I   = (const float*)d_in[0];   // input_spikes (32,256,768)
    const float* W   = (const float*)d_in[1];   // weights (1536,1536)
    const float* WF  = (const float*)d_in[2];   // weights_FF (768,1536)
    const float* sf  = (const float*)d_in[3];   // scaling_factors (2,2)
    const float* sfF = (const float*)d_in[4];   // scaling_factors_FF (1,2)
    const int*   ct  = (const int*)d_in[5];     // cell_type_indices (1536)
    // d_in[6] cell_type_indices_FF: all zeros, folded into sfF indexing.

    uint8_t* ws = (uint8_t*)d_ws;
    uint64_t* recmask = (uint64_t*)ws;                       // 1,572,864 B
    uint32_t* recflag = (uint32_t*)(ws + 32 * 256 * 24 * 8); // + 786,432 B

    snn_lif_kernel<<<dim3(256), dim3(768), 0, stream>>>(
        I, W, WF, sf, sfF, ct, (float*)d_out, recmask, recflag);
}

// Round 3
// 874.745 us; speedup vs baseline: 5.2063x; 5.2063x over previous
//
#include <hip/hip_runtime.h>
#include <stdint.h>

// Conductance-LIF network, persistent event-driven kernel. Round 3.
//
// KEY FIX vs rounds 1/2: the spike-exchange spin previously used agent-scope
// ACQUIRE loads — each poll iteration emits buffer_inv, invalidating the
// XCD's L1+L2 and destroying W residency (VALUBusy 2.5%, every gather at L3
// latency). Now flag+data live in ONE 64-bit word: high32 = step tag (t+1),
// low32 = 32 spike bits. Producer: relaxed agent-scope atomic store (writes
// through to the coherence point). Consumer: relaxed agent-scope atomic spin;
// a tag match validates the spike bits carried by the SAME load. No acquire,
// no release, no cache invalidates anywhere -> per-XCD W slice (1.77 MB)
// stays L2-resident and gathers are L2 hits.
//
// Mapping: j = blockIdx&7 (column slice -> XCD under %8 round-robin dispatch),
// b = blockIdx>>3 (batch). Gather: wave = K-phase (12-way), lanes 0..47 load
// one float4 each -> one contiguous 768 B segment per wave instruction.
// Spikes binary -> matmuls are row-sums over spiking sets; synapses 0,1 share
// the ct0 pre-mask (two recurrent sums z0,z1 + FF sum); scaling factors are
// (pre-ct,post-ct) separable -> applied post-sum.
//
// recpub tags are 1..256 (poison 0xAAAAAAAA never matches; harness re-poisons
// d_ws before every launch so no stale tags). All 256 blocks co-resident
// (3072 waves << 8192 wave slots) -> spin is deadlock-free.

__global__ __launch_bounds__(768) void snn_lif_kernel(
    const float* __restrict__ I,     // [32][256][768] input spikes (0/1)
    const float* __restrict__ W,     // [1536][1536] recurrent weights (row = pre)
    const float* __restrict__ WF,    // [768][1536]  FF weights (row = input)
    const float* __restrict__ sf,    // [2][2] scaling (pre ct, post ct)
    const float* __restrict__ sfF,   // [1][2] FF scaling (post ct)
    const int*   __restrict__ ct,    // [1536] cell type 0/1
    float* __restrict__ out,         // spk [32][256][1536] then volt [...]
    uint64_t* __restrict__ recpub)   // [32][256][48]: (tag<<32)|spike-bits
{
    const int tid = threadIdx.x;
    const int j   = blockIdx.x & 7;    // column-slice id -> XCD under %8 RR
    const int b   = blockIdx.x >> 3;   // batch
    const int wv  = tid >> 6;          // wave 0..11 (= K-phase in phase B)
    const int wl  = tid & 63;          // lane

    __shared__ uint32_t ent[3840];         // L0:[0,1536) L1:[1536,3072) F:[3072,3840)
    __shared__ float    part[3][12][192];  // per-K-phase partial sums
    __shared__ uint32_t totals_sh;
    __shared__ uint32_t ctm32_sh[48];      // cell-type bits per 32-neuron word
    __shared__ uint64_t fmask_sh[12];      // this-step FF spike mask

    // ---- cell-type bitmask via block-wide ballots ----
    for (int r = 0; r < 2; ++r) {
        int c = ct[r * 768 + tid];
        uint64_t bal = __ballot(c != 0);
        if (wl == 0) {
            ctm32_sh[r * 24 + wv * 2]     = (uint32_t)bal;
            ctm32_sh[r * 24 + wv * 2 + 1] = (uint32_t)(bal >> 32);
        }
    }
    __syncthreads();

    // ---- owner-neuron constants (threads 0..191 own neuron m) ----
    const int m = j * 192 + ((tid < 192) ? tid : 0);
    const int   myct = ct[m];
    const float s0m  = sf[myct];
    const float s1m  = sf[2 + myct];
    const float sFm  = sfF[myct];
    const float lc   = (myct == 0) ? (1.0f / 200.0f) : (1.0f / 100.0f);
    const float refsteps = (myct == 0) ? 2.0f : 1.0f;
    const float ar0 = expf(-1.0f / 0.5f),  ad0 = expf(-1.0f / 2.0f);
    const float ar1 = expf(-1.0f / 2.0f),  ad1 = expf(-1.0f / 100.0f);
    const float ar2 = expf(-1.0f / 0.5f),  ad2 = expf(-1.0f / 5.0f);
    const float arF = expf(-1.0f / 0.5f),  adF = expf(-1.0f / 2.0f);

    float U = -65.0f, refc = 0.0f;
    float x0 = 0, g0 = 0, x1 = 0, g1 = 0, x2 = 0, g2 = 0, xF = 0, gF = 0;

    const uint32_t ctw = (wl < 48) ? ctm32_sh[wl] : 0u;  // wave-0 scan uses it
    const int btbase = b * 256;

    for (int t = 0; t < 256; ++t) {
        // ---- FF spike ballot for this step (local data only) ----
        float iv = __builtin_nontemporal_load(
            &I[(uint32_t)(btbase + t) * 768u + (uint32_t)tid]);
        uint64_t fb = __ballot(iv > 0.5f);
        if (wl == 0) fmask_sh[wv] = fb;
        __syncthreads();   // (c)

        // ---- phase A (wave 0): poll siblings' spikes, build entry lists ----
        if (wv == 0) {
            uint32_t sm = 0;
            uint64_t fm = 0;
            uint32_t c0 = 0, c1 = 0, cF = 0;
            if (wl < 48) {
                if (t > 0) {
                    const uint32_t fi = (uint32_t)(btbase + t - 1) * 48u + (uint32_t)wl;
                    uint64_t v;
                    do {
                        v = __hip_atomic_load(&recpub[fi], __ATOMIC_RELAXED,
                                              __HIP_MEMORY_SCOPE_AGENT);
                    } while ((uint32_t)(v >> 32) != (uint32_t)t);  // tag of step t-1 is t
                    sm = (uint32_t)v;   // spike bits carried by the SAME load
                }
                c0 = __popc(sm & ~ctw);
                c1 = __popc(sm & ctw);
            } else if (wl < 60) {
                fm = fmask_sh[wl - 48];
                cF = __popcll(fm);
            }
            uint32_t pack = c0 | (c1 << 11) | (cF << 22);   // 11/11/10-bit fields
            uint32_t incl = pack;
            #pragma unroll
            for (int d = 1; d < 64; d <<= 1) {
                uint32_t u = __shfl_up(incl, d, 64);
                if (wl >= d) incl += u;
            }
            const uint32_t excl = incl - pack;
            if (wl == 59) totals_sh = incl;
            uint32_t p0 = excl & 0x7FFu;
            uint32_t p1 = 1536u + ((excl >> 11) & 0x7FFu);
            uint32_t pF = 3072u + (excl >> 22);
            if (wl < 48) {
                uint32_t mm = sm;
                const uint32_t lanebase = (uint32_t)wl * 32u * 1536u;
                while (mm) {
                    const int bit = __builtin_ctz(mm);
                    mm &= mm - 1;
                    const uint32_t off = lanebase + (uint32_t)bit * 1536u;
                    if ((ctw >> bit) & 1u) ent[p1++] = off;
                    else                   ent[p0++] = off;
                }
            } else if (wl < 60) {
                uint64_t mm = fm;
                const uint32_t lanebase = (uint32_t)(wl - 48) * 64u * 1536u;
                while (mm) {
                    const int bit = __builtin_ctzll(mm);
                    mm &= mm - 1;
                    ent[pF++] = lanebase + (uint32_t)bit * 1536u;
                }
            }
        }
        __syncthreads();   // (b)

        // ---- phase B: float4 gather; wave = K-phase (12-way), lanes 0..47 ----
        const uint32_t tp = totals_sh;
        const uint32_t t0 = tp & 0x7FFu;
        const uint32_t t1 = (tp >> 11) & 0x7FFu;
        const uint32_t tF = tp >> 22;
        if (wl < 48) {
            const uint32_t colv = (uint32_t)(j * 48 + wl);  // float4 index in a row
            float4 z0 = make_float4(0.f, 0.f, 0.f, 0.f);
            float4 z1 = z0, zF = z0;
            #pragma unroll 4
            for (uint32_t i = (uint32_t)wv; i < t0; i += 12u) {
                const float4 w = ((const float4*)(W + ent[i]))[colv];
                z0.x += w.x; z0.y += w.y; z0.z += w.z; z0.w += w.w;
            }
            #pragma unroll 4
            for (uint32_t i = (uint32_t)wv; i < t1; i += 12u) {
                const float4 w = ((const float4*)(W + ent[1536u + i]))[colv];
                z1.x += w.x; z1.y += w.y; z1.z += w.z; z1.w += w.w;
            }
            #pragma unroll 4
            for (uint32_t i = (uint32_t)wv; i < tF; i += 12u) {
                const float4 w = ((const float4*)(WF + ent[3072u + i]))[colv];
                zF.x += w.x; zF.y += w.y; zF.z += w.z; zF.w += w.w;
            }
            *(float4*)&part[0][wv][wl * 4] = z0;
            *(float4*)&part[1][wv][wl * 4] = z1;
            *(float4*)&part[2][wv][wl * 4] = zF;
        }
        __syncthreads();   // (a)

        // ---- phase C (threads 0..191): reduce, LIF update, publish ----
        if (tid < 192) {
            float z0s = 0.f, z1s = 0.f, zFs = 0.f;
            #pragma unroll
            for (int k = 0; k < 12; ++k) {
                z0s += part[0][k][tid];
                z1s += part[1][k][tid];
                zFs += part[2][k][tid];
            }
            z0s *= s0m; z1s *= s1m; zFs *= sFm;
            x0 = ar0 * x0 + z0s;  g0 = ad0 * g0 + x0;   // syn0 (pre ct0)
            x1 = ar1 * x1 + z0s;  g1 = ad1 * g1 + x1;   // syn1 (pre ct0, same z0)
            x2 = ar2 * x2 + z1s;  g2 = ad2 * g2 + x2;   // syn2 (pre ct1)
            xF = arF * xF + zFs;  gF = adF * gF + xF;   // feed-forward
            const float gtot = g0 + 0.5f * g1 + g2 + gF;   // gbar=[1,.5,1], FF 1
            const float gE   = -70.0f * g2;                // gbar*Erev=[0,0,-70], FF 0
            const float Isyn = gE - gtot * U;
            float Un = U + lc * (10.0f * (-65.0f - U) + Isyn);
            if (refc > 0.0f) Un = -65.0f;
            refc = fmaxf(refc - 1.0f, 0.0f);
            const bool s = (Un - (-50.0f)) >= 0.0f;
            const float Uo = s ? -65.0f : Un;
            refc = s ? refsteps : refc;
            U = Uo;
            const uint32_t oidx = (uint32_t)(btbase + t) * 1536u + (uint32_t)m;
            __builtin_nontemporal_store(s ? 1.0f : 0.0f, &out[oidx]);
            __builtin_nontemporal_store(Uo, &out[12582912u + oidx]);
            // publish: waves 0..2 cover 64 consecutive neurons each; lanes 0/32
            // store (tag<<32)|half — flag and data in one atomic word.
            const uint64_t bal = __ballot(s);
            if (wl == 0 || wl == 32) {
                const uint32_t half = (wl == 0) ? (uint32_t)bal : (uint32_t)(bal >> 32);
                const uint32_t word = (uint32_t)(j * 6 + wv * 2) + (wl == 32 ? 1u : 0u);
                const uint32_t widx = (uint32_t)(btbase + t) * 48u + word;
                const uint64_t v = ((uint64_t)(uint32_t)(t + 1) << 32) | half;
                __hip_atomic_store(&recpub[widx], v, __ATOMIC_RELAXED,
                                   __HIP_MEMORY_SCOPE_AGENT);
            }
        }
    }
}

extern "C" void kernel_launch(void* const* d_in, const int* in_sizes, int n_in,
                              void* d_out, int out_size, void* d_ws, size_t ws_size,
                              hipStream_t stream) {
    const float* I   = (const float*)d_in[0];   // input_spikes (32,256,768)
    const float* W   = (const float*)d_in[1];   // weights (1536,1536)
    const float* WF  = (const float*)d_in[2];   // weights_FF (768,1536)
    const float* sf  = (const float*)d_in[3];   // scaling_factors (2,2)
    const float* sfF = (const float*)d_in[4];   // scaling_factors_FF (1,2)
    const int*   ct  = (const int*)d_in[5];     // cell_type_indices (1536)
    // d_in[6] cell_type_indices_FF: all zeros, folded into sfF indexing.

    uint64_t* recpub = (uint64_t*)d_ws;   // 32*256*48*8 = 3,145,728 B

    snn_lif_kernel<<<dim3(256), dim3(768), 0, stream>>>(
        I, W, WF, sf, sfF, ct, (float*)d_out, recpub);
}

// Round 4
// 845.304 us; speedup vs baseline: 5.3876x; 1.0348x over previous
//
#include <hip/hip_runtime.h>
#include <stdint.h>

// Conductance-LIF network, persistent event-driven kernel. Round 4.
//
// Round-3 post-mortem: chain was fully serial — poll (~900+ cyc, agent-scope
// atomics are serviced at the fabric/HBM), cold I-load (~900 cyc), gather,
// update — 3.0 us/step with all pipes <15% busy. FETCH residue (~75 MB) =
// failed-poll HBM rounds.
//
// Round-4 structure (3 barriers/step), software-pipelined:
//   tail of step t-1: publish spikes FIRST, then build FF entry list for step
//     t from the already-balloted I[t] mask (local data, known ahead).
//   top barrier
//   phase P: wave 0 polls remote spike words (s_sleep backoff) and builds the
//     recurrent entry lists WHILE waves 1..11 gather the FF rows; everyone
//     issues the I[t+1] prefetch first so it's in flight behind the phase.
//   barrier; phase R: all 12 waves gather recurrent rows (unroll 8, L2-hit).
//   ballot I[t+1] -> fmask; barrier; tail (see above) + LIF update + stores.
//
// Sync remains the round-3 fence-free scheme: flag+data in ONE 64-bit word
// (high32 = step tag t+1, low32 = 32 spike bits), relaxed agent-scope atomics
// only — no acquire/release, no buffer_inv, so the per-XCD W column slice
// (1.77 MB) stays L2-resident. j = blockIdx&7 keeps one column slice per XCD
// under %8 round-robin dispatch (perf heuristic only, never correctness).
// Tags 1..256 never match the 0xAAAAAAAA ws poison; all 256 blocks are
// co-resident (3072 waves << 8192 slots) so spinning is deadlock-free.

__global__ __launch_bounds__(768) void snn_lif_kernel(
    const float* __restrict__ I,     // [32][256][768] input spikes (0/1)
    const float* __restrict__ W,     // [1536][1536] recurrent weights (row = pre)
    const float* __restrict__ WF,    // [768][1536]  FF weights (row = input)
    const float* __restrict__ sf,    // [2][2] scaling (pre ct, post ct)
    const float* __restrict__ sfF,   // [1][2] FF scaling (post ct)
    const int*   __restrict__ ct,    // [1536] cell type 0/1
    float* __restrict__ out,         // spk [32][256][1536] then volt [...]
    uint64_t* __restrict__ recpub)   // [32][256][48]: (tag<<32)|spike-bits
{
    const int tid = threadIdx.x;
    const int j   = blockIdx.x & 7;    // column-slice id -> XCD under %8 RR
    const int b   = blockIdx.x >> 3;   // batch
    const int wv  = tid >> 6;          // wave 0..11
    const int wl  = tid & 63;          // lane

    __shared__ uint32_t ent[3840];          // rec0:[0,1536) rec1:[1536,3072) FF:[3072,3840)
    __shared__ float    partF[11][192];     // FF partials (waves 1..11)
    __shared__ float    part0[12][192];     // rec ct0 partials
    __shared__ float    part1[12][192];     // rec ct1 partials
    __shared__ uint32_t totals_sh;          // packed t0 | t1<<16
    __shared__ uint32_t tF_sh;              // FF list length
    __shared__ uint32_t ctm32_sh[48];       // cell-type bits per 32-neuron word
    __shared__ uint64_t fmask_sh[12];       // next-step FF spike mask

    // ---- cell-type bitmask via block-wide ballots ----
    for (int r = 0; r < 2; ++r) {
        int c = ct[r * 768 + tid];
        uint64_t bal = __ballot(c != 0);
        if (wl == 0) {
            ctm32_sh[r * 24 + wv * 2]     = (uint32_t)bal;
            ctm32_sh[r * 24 + wv * 2 + 1] = (uint32_t)(bal >> 32);
        }
    }
    __syncthreads();

    // ---- owner-neuron constants (threads 0..191 own neuron m) ----
    const int m = j * 192 + ((tid < 192) ? tid : 0);
    const int   myct = ct[m];
    const float s0m  = sf[myct];
    const float s1m  = sf[2 + myct];
    const float sFm  = sfF[myct];
    const float lc   = (myct == 0) ? (1.0f / 200.0f) : (1.0f / 100.0f);
    const float refsteps = (myct == 0) ? 2.0f : 1.0f;
    const float ar0 = expf(-1.0f / 0.5f),  ad0 = expf(-1.0f / 2.0f);
    const float ar1 = expf(-1.0f / 2.0f),  ad1 = expf(-1.0f / 100.0f);
    const float ar2 = expf(-1.0f / 0.5f),  ad2 = expf(-1.0f / 5.0f);
    const float arF = expf(-1.0f / 0.5f),  adF = expf(-1.0f / 2.0f);

    float U = -65.0f, refc = 0.0f;
    float x0 = 0, g0 = 0, x1 = 0, g1 = 0, x2 = 0, g2 = 0, xF = 0, gF = 0;

    const uint32_t ctw = (wl < 48) ? ctm32_sh[wl] : 0u;
    const int btbase = b * 256;
    const uint32_t colv = (uint32_t)(j * 48 + wl);   // float4 index in a row

    // ---- preamble: ballot I[0], build FF list for t=0 ----
    {
        float iv0 = __builtin_nontemporal_load(&I[(uint32_t)btbase * 768u + (uint32_t)tid]);
        uint64_t fb = __ballot(iv0 > 0.5f);
        if (wl == 0) fmask_sh[wv] = fb;
    }
    __syncthreads();
    if (wv == 0) {
        uint64_t fm = 0; uint32_t cF = 0;
        if (wl < 12) { fm = fmask_sh[wl]; cF = __popcll(fm); }
        uint32_t incl = cF;
        #pragma unroll
        for (int d = 1; d < 64; d <<= 1) {
            uint32_t u = __shfl_up(incl, d, 64);
            if (wl >= d) incl += u;
        }
        if (wl == 11) tF_sh = incl;
        if (wl < 12) {
            uint32_t pF = 3072u + (incl - cF);
            const uint32_t lanebase = (uint32_t)wl * 64u * 1536u;
            while (fm) {
                const int bit = __builtin_ctzll(fm);
                fm &= fm - 1;
                ent[pF++] = lanebase + (uint32_t)bit * 1536u;
            }
        }
    }

    for (int t = 0; t < 256; ++t) {
        __syncthreads();   // top: entF/tF (built in prior tail) + fmask coherent

        // prefetch next-step input (in flight behind phase P / R)
        float iv_next = 0.0f;
        if (t < 255)
            iv_next = __builtin_nontemporal_load(
                &I[(uint32_t)(btbase + t + 1) * 768u + (uint32_t)tid]);

        // ---- phase P: wave 0 polls + builds rec lists; waves 1..11 gather FF ----
        if (wv == 0) {
            uint32_t sm = 0;
            if (wl < 48 && t > 0) {
                const uint32_t fi = (uint32_t)(btbase + t - 1) * 48u + (uint32_t)wl;
                for (;;) {
                    uint64_t v = __hip_atomic_load(&recpub[fi], __ATOMIC_RELAXED,
                                                   __HIP_MEMORY_SCOPE_AGENT);
                    if ((uint32_t)(v >> 32) == (uint32_t)t) { sm = (uint32_t)v; break; }
                    __builtin_amdgcn_s_sleep(1);
                }
            }
            const uint32_t c0 = __popc(sm & ~ctw);
            const uint32_t c1 = __popc(sm & ctw);
            uint32_t pack = c0 | (c1 << 16);
            uint32_t incl = pack;
            #pragma unroll
            for (int d = 1; d < 64; d <<= 1) {
                uint32_t u = __shfl_up(incl, d, 64);
                if (wl >= d) incl += u;
            }
            const uint32_t excl = incl - pack;
            if (wl == 47) totals_sh = incl;
            if (wl < 48) {
                uint32_t p0 = excl & 0xFFFFu;
                uint32_t p1 = 1536u + (excl >> 16);
                uint32_t mm = sm;
                const uint32_t lanebase = (uint32_t)wl * 32u * 1536u;
                while (mm) {
                    const int bit = __builtin_ctz(mm);
                    mm &= mm - 1;
                    const uint32_t off = lanebase + (uint32_t)bit * 1536u;
                    if ((ctw >> bit) & 1u) ent[p1++] = off;
                    else                   ent[p0++] = off;
                }
            }
        } else if (wl < 48) {
            const uint32_t tF = tF_sh;
            float4 zF = make_float4(0.f, 0.f, 0.f, 0.f);
            #pragma unroll 4
            for (uint32_t i = (uint32_t)(wv - 1); i < tF; i += 11u) {
                const float4 w = ((const float4*)(WF + ent[3072u + i]))[colv];
                zF.x += w.x; zF.y += w.y; zF.z += w.z; zF.w += w.w;
            }
            *(float4*)&partF[wv - 1][wl * 4] = zF;
        }
        __syncthreads();   // rec lists ready

        // ---- phase R: all 12 waves gather recurrent rows ----
        const uint32_t tp = totals_sh;
        const uint32_t t0 = tp & 0xFFFFu;
        const uint32_t t1 = tp >> 16;
        if (wl < 48) {
            float4 z0 = make_float4(0.f, 0.f, 0.f, 0.f);
            float4 z1 = z0;
            #pragma unroll 8
            for (uint32_t i = (uint32_t)wv; i < t0; i += 12u) {
                const float4 w = ((const float4*)(W + ent[i]))[colv];
                z0.x += w.x; z0.y += w.y; z0.z += w.z; z0.w += w.w;
            }
            #pragma unroll 8
            for (uint32_t i = (uint32_t)wv; i < t1; i += 12u) {
                const float4 w = ((const float4*)(W + ent[1536u + i]))[colv];
                z1.x += w.x; z1.y += w.y; z1.z += w.z; z1.w += w.w;
            }
            *(float4*)&part0[wv][wl * 4] = z0;
            *(float4*)&part1[wv][wl * 4] = z1;
        }
        // ballot next-step FF mask (value already in flight)
        {
            uint64_t fb = __ballot(iv_next > 0.5f);
            if (wl == 0) fmask_sh[wv] = fb;
        }
        __syncthreads();   // partials + fmask ready

        // ---- tail: LIF update + publish (first!), then FF list for t+1 ----
        if (tid < 192) {
            float z0s = 0.f, z1s = 0.f, zFs = 0.f;
            #pragma unroll
            for (int k = 0; k < 11; ++k) zFs += partF[k][tid];
            #pragma unroll
            for (int k = 0; k < 12; ++k) { z0s += part0[k][tid]; z1s += part1[k][tid]; }
            z0s *= s0m; z1s *= s1m; zFs *= sFm;
            x0 = ar0 * x0 + z0s;  g0 = ad0 * g0 + x0;   // syn0 (pre ct0)
            x1 = ar1 * x1 + z0s;  g1 = ad1 * g1 + x1;   // syn1 (pre ct0, same z0)
            x2 = ar2 * x2 + z1s;  g2 = ad2 * g2 + x2;   // syn2 (pre ct1)
            xF = arF * xF + zFs;  gF = adF * gF + xF;   // feed-forward
            const float gtot = g0 + 0.5f * g1 + g2 + gF;   // gbar=[1,.5,1], FF 1
            const float gE   = -70.0f * g2;                // gbar*Erev=[0,0,-70], FF 0
            const float Isyn = gE - gtot * U;
            float Un = U + lc * (10.0f * (-65.0f - U) + Isyn);
            if (refc > 0.0f) Un = -65.0f;
            refc = fmaxf(refc - 1.0f, 0.0f);
            const bool s = (Un - (-50.0f)) >= 0.0f;
            // publish ASAP: waves 0..2 cover 64 consecutive neurons each;
            // lanes 0/32 store (tag<<32)|half — flag and data in one word.
            const uint64_t bal = __ballot(s);
            if (wl == 0 || wl == 32) {
                const uint32_t half = (wl == 0) ? (uint32_t)bal : (uint32_t)(bal >> 32);
                const uint32_t word = (uint32_t)(j * 6 + wv * 2) + (wl == 32 ? 1u : 0u);
                const uint32_t widx = (uint32_t)(btbase + t) * 48u + word;
                const uint64_t v = ((uint64_t)(uint32_t)(t + 1) << 32) | half;
                __hip_atomic_store(&recpub[widx], v, __ATOMIC_RELAXED,
                                   __HIP_MEMORY_SCOPE_AGENT);
            }
            const float Uo = s ? -65.0f : Un;
            refc = s ? refsteps : refc;
            U = Uo;
            const uint32_t oidx = (uint32_t)(btbase + t) * 1536u + (uint32_t)m;
            __builtin_nontemporal_store(s ? 1.0f : 0.0f, &out[oidx]);
            __builtin_nontemporal_store(Uo, &out[12582912u + oidx]);
        }
        if (wv == 0 && t < 255) {   // build FF entry list for step t+1
            uint64_t fm = 0; uint32_t cF = 0;
            if (wl < 12) { fm = fmask_sh[wl]; cF = __popcll(fm); }
            uint32_t incl = cF;
            #pragma unroll
            for (int d = 1; d < 64; d <<= 1) {
                uint32_t u = __shfl_up(incl, d, 64);
                if (wl >= d) incl += u;
            }
            if (wl == 11) tF_sh = incl;
            if (wl < 12) {
                uint32_t pF = 3072u + (incl - cF);
                const uint32_t lanebase = (uint32_t)wl * 64u * 1536u;
                while (fm) {
                    const int bit = __builtin_ctzll(fm);
                    fm &= fm - 1;
                    ent[pF++] = lanebase + (uint32_t)bit * 1536u;
                }
            }
        }
    }
}

extern "C" void kernel_launch(void* const* d_in, const int* in_sizes, int n_in,
                              void* d_out, int out_size, void* d_ws, size_t ws_size,
                              hipStream_t stream) {
    const float* I   = (const float*)d_in[0];   // input_spikes (32,256,768)
    const float* W   = (const float*)d_in[1];   // weights (1536,1536)
    const float* WF  = (const float*)d_in[2];   // weights_FF (768,1536)
    const float* sf  = (const float*)d_in[3];   // scaling_factors (2,2)
    const float* sfF = (const float*)d_in[4];   // scaling_factors_FF (1,2)
    const int*   ct  = (const int*)d_in[5];     // cell_type_indices (1536)
    // d_in[6] cell_type_indices_FF: all zeros, folded into sfF indexing.

    uint64_t* recpub = (uint64_t*)d_ws;   // 32*256*48*8 = 3,145,728 B

    snn_lif_kernel<<<dim3(256), dim3(768), 0, stream>>>(
        I, W, WF, sf, sfF, ct, (float*)d_out, recpub);
}

// Round 5
// 839.239 us; speedup vs baseline: 5.4265x; 1.0072x over previous
//
#include <hip/hip_runtime.h>
#include <stdint.h>

// Conductance-LIF network, persistent event-driven kernel. Round 5.
//
// Round-4 post-mortem: 1 block/CU => the ~1.8 us/step of exposed fabric-level
// poll latency had NOTHING co-resident to overlap with (FF gather is only
// ~0.2 us of work). Fix: 512 blocks x 384 threads = 16 column slices x 96
// neurons => 2 blocks/CU, with a mapping hedged so that under either likely
// dispatch packing (co-resident pairs n,n+8 or n,n+256) the two blocks on a
// CU belong to DIFFERENT batches (independent sync chains): one block's poll
// overlaps the other's gather. Slice->XCD affinity is kept (XCD x hosts
// slices x and x+8: 1.77 MB of W/WF columns, L2-resident).
//
//   x = blockIdx & 7 (XCD under %8 RR); r = blockIdx >> 3; half = r >> 5;
//   slice j = x + 8*half; batch b = ((r & 31) + 16*half) & 31.
//
// Sync stays fence-free (round 3): flag+data in ONE 64-bit word (hi32 = step
// tag t+1, lo32 = 32 spike bits), relaxed agent-scope atomics only — no
// acquire/release, no buffer_inv, L2 stays warm. Tags 1..256 never collide
// with 0xAAAAAAAA ws poison. All 512 blocks co-resident (3072 waves << 8192;
// 2x28 KB LDS << 160 KB) => spinning is deadlock-free.
//
// Gather: 48 active lanes/wave = 2 rows x 24 float4 (each row segment is a
// contiguous 384 B) — 12 K-phases over 6 waves for recurrent, 10 phases over
// waves 1..5 for FF (wave 0 polls + builds lists meanwhile). Spikes binary =>
// matmuls are row sums; synapses 0,1 share the ct0 pre-mask (z0,z1 + FF);
// scaling factors are (pre-ct,post-ct) separable => applied post-sum.

__global__ __launch_bounds__(384) void snn_lif_kernel(
    const float* __restrict__ I,     // [32][256][768] input spikes (0/1)
    const float* __restrict__ W,     // [1536][1536] recurrent weights (row = pre)
    const float* __restrict__ WF,    // [768][1536]  FF weights (row = input)
    const float* __restrict__ sf,    // [2][2] scaling (pre ct, post ct)
    const float* __restrict__ sfF,   // [1][2] FF scaling (post ct)
    const int*   __restrict__ ct,    // [1536] cell type 0/1
    float* __restrict__ out,         // spk [32][256][1536] then volt [...]
    uint64_t* __restrict__ recpub)   // [32][256][48]: (tag<<32)|spike-bits
{
    const int tid = threadIdx.x;
    const int x    = blockIdx.x & 7;          // XCD slot under %8 RR
    const int r    = blockIdx.x >> 3;
    const int half = r >> 5;
    const int j    = x + 8 * half;            // column slice 0..15 (96 cols)
    const int b    = ((r & 31) + (half << 4)) & 31;   // batch, co-resident-diverse
    const int wv  = tid >> 6;                 // wave 0..5
    const int wl  = tid & 63;                 // lane

    __shared__ uint32_t ent[3840];        // rec0:[0,1536) rec1:[1536,3072) FF:[3072,3840)
    __shared__ float    partF[10][96];    // FF partials (waves 1..5 x 2 rows)
    __shared__ float    part0[12][96];    // rec ct0 partials
    __shared__ float    part1[12][96];    // rec ct1 partials
    __shared__ uint32_t totals_sh;        // packed t0 | t1<<16
    __shared__ uint32_t tF_sh;            // FF list length
    __shared__ uint32_t ctm32_sh[48];     // cell-type bits per 32-neuron word
    __shared__ uint64_t fmask_sh[12];     // next-step FF spike mask

    // ---- cell-type bitmask via block-wide ballots (4 x 384) ----
    for (int rr = 0; rr < 4; ++rr) {
        int c = ct[rr * 384 + tid];
        uint64_t bal = __ballot(c != 0);
        if (wl == 0) {
            ctm32_sh[rr * 12 + wv * 2]     = (uint32_t)bal;
            ctm32_sh[rr * 12 + wv * 2 + 1] = (uint32_t)(bal >> 32);
        }
    }
    __syncthreads();

    // ---- owner-neuron constants (threads 0..95 own neuron m) ----
    const int m = j * 96 + ((tid < 96) ? tid : 0);
    const int   myct = ct[m];
    const float s0m  = sf[myct];
    const float s1m  = sf[2 + myct];
    const float sFm  = sfF[myct];
    const float lc   = (myct == 0) ? (1.0f / 200.0f) : (1.0f / 100.0f);
    const float refsteps = (myct == 0) ? 2.0f : 1.0f;
    const float ar0 = expf(-1.0f / 0.5f),  ad0 = expf(-1.0f / 2.0f);
    const float ar1 = expf(-1.0f / 2.0f),  ad1 = expf(-1.0f / 100.0f);
    const float ar2 = expf(-1.0f / 0.5f),  ad2 = expf(-1.0f / 5.0f);
    const float arF = expf(-1.0f / 0.5f),  adF = expf(-1.0f / 2.0f);

    float U = -65.0f, refc = 0.0f;
    float x0 = 0, g0 = 0, x1 = 0, g1 = 0, x2 = 0, g2 = 0, xF = 0, gF = 0;

    const uint32_t ctw = (wl < 48) ? ctm32_sh[wl] : 0u;
    const int btbase = b * 256;
    // gather lane geometry: 48 lanes = 2 rows x 24 float4 (row seg = 384 B)
    const int row_sub = (wl >= 24) ? 1 : 0;
    const uint32_t colv4 = (uint32_t)(j * 24 + (wl - row_sub * 24)); // float4 idx in row

    // ---- preamble: ballot I[0], build FF list for t=0 ----
    {
        float iva = __builtin_nontemporal_load(&I[(uint32_t)btbase * 768u + (uint32_t)tid]);
        float ivb = __builtin_nontemporal_load(&I[(uint32_t)btbase * 768u + 384u + (uint32_t)tid]);
        uint64_t fa = __ballot(iva > 0.5f);
        uint64_t fb = __ballot(ivb > 0.5f);
        if (wl == 0) { fmask_sh[wv] = fa; fmask_sh[wv + 6] = fb; }
    }
    __syncthreads();
    if (wv == 0) {
        uint64_t fm = 0; uint32_t cF = 0;
        if (wl < 12) { fm = fmask_sh[wl]; cF = __popcll(fm); }
        uint32_t incl = cF;
        #pragma unroll
        for (int d = 1; d < 64; d <<= 1) {
            uint32_t u = __shfl_up(incl, d, 64);
            if (wl >= d) incl += u;
        }
        if (wl == 11) tF_sh = incl;
        if (wl < 12) {
            uint32_t pF = 3072u + (incl - cF);
            const uint32_t lanebase = (uint32_t)wl * 64u * 1536u;
            while (fm) {
                const int bit = __builtin_ctzll(fm);
                fm &= fm - 1;
                ent[pF++] = lanebase + (uint32_t)bit * 1536u;
            }
        }
    }

    for (int t = 0; t < 256; ++t) {
        __syncthreads();   // top: entF/tF (from prior tail) + fmask coherent

        // prefetch next-step input (in flight behind phases P and R)
        float iva_n = 0.0f, ivb_n = 0.0f;
        if (t < 255) {
            const uint32_t base = (uint32_t)(btbase + t + 1) * 768u;
            iva_n = __builtin_nontemporal_load(&I[base + (uint32_t)tid]);
            ivb_n = __builtin_nontemporal_load(&I[base + 384u + (uint32_t)tid]);
        }

        // ---- phase P: wave 0 polls + builds rec lists; waves 1..5 gather FF ----
        if (wv == 0) {
            uint32_t sm = 0;
            if (wl < 48 && t > 0) {
                const uint32_t fi = (uint32_t)(btbase + t - 1) * 48u + (uint32_t)wl;
                for (;;) {
                    uint64_t v = __hip_atomic_load(&recpub[fi], __ATOMIC_RELAXED,
                                                   __HIP_MEMORY_SCOPE_AGENT);
                    if ((uint32_t)(v >> 32) == (uint32_t)t) { sm = (uint32_t)v; break; }
                    __builtin_amdgcn_s_sleep(1);
                }
            }
            const uint32_t c0 = __popc(sm & ~ctw);
            const uint32_t c1 = __popc(sm & ctw);
            uint32_t pack = c0 | (c1 << 16);
            uint32_t incl = pack;
            #pragma unroll
            for (int d = 1; d < 64; d <<= 1) {
                uint32_t u = __shfl_up(incl, d, 64);
                if (wl >= d) incl += u;
            }
            const uint32_t excl = incl - pack;
            if (wl == 47) totals_sh = incl;
            if (wl < 48) {
                uint32_t p0 = excl & 0xFFFFu;
                uint32_t p1 = 1536u + (excl >> 16);
                uint32_t mm = sm;
                const uint32_t lanebase = (uint32_t)wl * 32u * 1536u;
                while (mm) {
                    const int bit = __builtin_ctz(mm);
                    mm &= mm - 1;
                    const uint32_t off = lanebase + (uint32_t)bit * 1536u;
                    if ((ctw >> bit) & 1u) ent[p1++] = off;
                    else                   ent[p0++] = off;
                }
            }
        } else if (wl < 48) {
            const uint32_t tF = tF_sh;
            const uint32_t phase = (uint32_t)((wv - 1) * 2 + row_sub);  // 0..9
            float4 zF = make_float4(0.f, 0.f, 0.f, 0.f);
            #pragma unroll 4
            for (uint32_t i = phase; i < tF; i += 10u) {
                const float4 w = ((const float4*)(WF + ent[3072u + i]))[colv4];
                zF.x += w.x; zF.y += w.y; zF.z += w.z; zF.w += w.w;
            }
            *(float4*)&partF[phase][(wl - row_sub * 24) * 4] = zF;
        }
        __syncthreads();   // rec lists ready

        // ---- phase R: all 6 waves gather recurrent rows (12 K-phases) ----
        const uint32_t tp = totals_sh;
        const uint32_t t0 = tp & 0xFFFFu;
        const uint32_t t1 = tp >> 16;
        if (wl < 48) {
            const uint32_t phase = (uint32_t)(wv * 2 + row_sub);  // 0..11
            float4 z0 = make_float4(0.f, 0.f, 0.f, 0.f);
            float4 z1 = z0;
            #pragma unroll 4
            for (uint32_t i = phase; i < t0; i += 12u) {
                const float4 w = ((const float4*)(W + ent[i]))[colv4];
                z0.x += w.x; z0.y += w.y; z0.z += w.z; z0.w += w.w;
            }
            #pragma unroll 4
            for (uint32_t i = phase; i < t1; i += 12u) {
                const float4 w = ((const float4*)(W + ent[1536u + i]))[colv4];
                z1.x += w.x; z1.y += w.y; z1.z += w.z; z1.w += w.w;
            }
            const int c4 = (wl - row_sub * 24) * 4;
            *(float4*)&part0[phase][c4] = z0;
            *(float4*)&part1[phase][c4] = z1;
        }
        // ballot next-step FF mask (values already in flight)
        {
            uint64_t fa = __ballot(iva_n > 0.5f);
            uint64_t fb = __ballot(ivb_n > 0.5f);
            if (wl == 0) { fmask_sh[wv] = fa; fmask_sh[wv + 6] = fb; }
        }
        __syncthreads();   // partials + fmask ready

        // ---- tail: LIF update + publish (first!), then FF list for t+1 ----
        if (tid < 96) {
            float z0s = 0.f, z1s = 0.f, zFs = 0.f;
            #pragma unroll
            for (int k = 0; k < 10; ++k) zFs += partF[k][tid];
            #pragma unroll
            for (int k = 0; k < 12; ++k) { z0s += part0[k][tid]; z1s += part1[k][tid]; }
            z0s *= s0m; z1s *= s1m; zFs *= sFm;
            x0 = ar0 * x0 + z0s;  g0 = ad0 * g0 + x0;   // syn0 (pre ct0)
            x1 = ar1 * x1 + z0s;  g1 = ad1 * g1 + x1;   // syn1 (pre ct0, same z0)
            x2 = ar2 * x2 + z1s;  g2 = ad2 * g2 + x2;   // syn2 (pre ct1)
            xF = arF * xF + zFs;  gF = adF * gF + xF;   // feed-forward
            const float gtot = g0 + 0.5f * g1 + g2 + gF;   // gbar=[1,.5,1], FF 1
            const float gE   = -70.0f * g2;                // gbar*Erev=[0,0,-70], FF 0
            const float Isyn = gE - gtot * U;
            float Un = U + lc * (10.0f * (-65.0f - U) + Isyn);
            if (refc > 0.0f) Un = -65.0f;
            refc = fmaxf(refc - 1.0f, 0.0f);
            const bool s = (Un - (-50.0f)) >= 0.0f;
            // publish ASAP: wave0 ballot -> words 0,1; wave1 (lanes 0..31) -> word 2
            const uint64_t bal = __ballot(s);
            if (wl == 0 || (wv == 0 && wl == 32)) {
                const uint32_t wib  = (wv == 0) ? ((wl == 32) ? 1u : 0u) : 2u;
                const uint32_t bits = (wl == 32) ? (uint32_t)(bal >> 32) : (uint32_t)bal;
                const uint32_t widx = (uint32_t)(btbase + t) * 48u + (uint32_t)(j * 3) + wib;
                const uint64_t v = ((uint64_t)(uint32_t)(t + 1) << 32) | bits;
                __hip_atomic_store(&recpub[widx], v, __ATOMIC_RELAXED,
                                   __HIP_MEMORY_SCOPE_AGENT);
            }
            const float Uo = s ? -65.0f : Un;
            refc = s ? refsteps : refc;
            U = Uo;
            const uint32_t oidx = (uint32_t)(btbase + t) * 1536u + (uint32_t)m;
            __builtin_nontemporal_store(s ? 1.0f : 0.0f, &out[oidx]);
            __builtin_nontemporal_store(Uo, &out[12582912u + oidx]);
        }
        if (wv == 0 && t < 255) {   // build FF entry list for step t+1
            uint64_t fm = 0; uint32_t cF = 0;
            if (wl < 12) { fm = fmask_sh[wl]; cF = __popcll(fm); }
            uint32_t incl = cF;
            #pragma unroll
            for (int d = 1; d < 64; d <<= 1) {
                uint32_t u = __shfl_up(incl, d, 64);
                if (wl >= d) incl += u;
            }
            if (wl == 11) tF_sh = incl;
            if (wl < 12) {
                uint32_t pF = 3072u + (incl - cF);
                const uint32_t lanebase = (uint32_t)wl * 64u * 1536u;
                while (fm) {
                    const int bit = __builtin_ctzll(fm);
                    fm &= fm - 1;
                    ent[pF++] = lanebase + (uint32_t)bit * 1536u;
                }
            }
        }
    }
}

extern "C" void kernel_launch(void* const* d_in, const int* in_sizes, int n_in,
                              void* d_out, int out_size, void* d_ws, size_t ws_size,
                              hipStream_t stream) {
    const float* I   = (const float*)d_in[0];   // input_spikes (32,256,768)
    const float* W   = (const float*)d_in[1];   // weights (1536,1536)
    const float* WF  = (const float*)d_in[2];   // weights_FF (768,1536)
    const float* sf  = (const float*)d_in[3];   // scaling_factors (2,2)
    const float* sfF = (const float*)d_in[4];   // scaling_factors_FF (1,2)
    const int*   ct  = (const int*)d_in[5];     // cell_type_indices (1536)
    // d_in[6] cell_type_indices_FF: all zeros, folded into sfF indexing.

    uint64_t* recpub = (uint64_t*)d_ws;   // 32*256*48*8 = 3,145,728 B

    snn_lif_kernel<<<dim3(512), dim3(384), 0, stream>>>(
        I, W, WF, sf, sfF, ct, (float*)d_out, recpub);
}

// Round 6
// 750.906 us; speedup vs baseline: 6.0649x; 1.1176x over previous
//
#include <hip/hip_runtime.h>
#include <stdint.h>

// Conductance-LIF network, persistent event-driven kernel. Round 6.
//
// Rounds 3/4/5 all sat at ~3.0 us/step regardless of structure: the step was a
// serial convoy — wait for ALL 48 spike words, build lists, barrier, gather,
// barrier, tail. This round FUSES detection and gathering per wave:
//
//   * 256 blocks x 768 threads: slice j = blockIdx&7 (192 cols, XCD-affine
//     under %8 round-robin so the 1.77 MB W/WF column slice stays L2-resident),
//     batch b = blockIdx>>3.
//   * Each of the 12 waves owns: its OWN FF word (the wave's own ballot of
//     I[t] — a register; no LDS mask, no entry lists anywhere) + 4 recurrent
//     spike words. The 4 words are polled concurrently (lanes 0..3, one load
//     instruction) and each word's <=32 rows are gathered THE MOMENT its tag
//     matches (readlane -> wave-uniform bit loop; 48 lanes x float4 = one
//     768 B contiguous row segment per iteration; ct0/ct1 accumulator chosen
//     by a wave-uniform branch). Late words hide behind early words' gather.
//   * ONE barrier per step (partials double-buffered in LDS), then tail:
//     12-way reduce, LIF update, publish FIRST, nontemporal output stores.
//
// Sync stays fence-free (round 3): flag+data in ONE 64-bit word (hi32 = step
// tag t+1 for step-t spikes, lo32 = 32 spike bits), relaxed agent-scope
// atomics only — no acquire/release, no buffer_inv, L2 stays warm. Tags
// 1..256 never collide with the 0xAAAAAAAA ws poison. All 256 blocks are
// co-resident (3072 waves << 8192 slots) and the publish for step t precedes
// any wait on step-t words (induction over t) -> no deadlock. Correctness
// never depends on block->XCD placement (that is a perf heuristic only).

__global__ __launch_bounds__(768) void snn_lif_kernel(
    const float* __restrict__ I,     // [32][256][768] input spikes (0/1)
    const float* __restrict__ W,     // [1536][1536] recurrent weights (row = pre)
    const float* __restrict__ WF,    // [768][1536]  FF weights (row = input)
    const float* __restrict__ sf,    // [2][2] scaling (pre ct, post ct)
    const float* __restrict__ sfF,   // [1][2] FF scaling (post ct)
    const int*   __restrict__ ct,    // [1536] cell type 0/1
    float* __restrict__ out,         // spk [32][256][1536] then volt [...]
    uint64_t* __restrict__ recpub)   // [32][256][48]: (tag<<32)|spike-bits
{
    const int tid = threadIdx.x;
    const int j   = blockIdx.x & 7;    // column slice -> XCD under %8 RR
    const int b   = blockIdx.x >> 3;   // batch
    const int wv  = tid >> 6;          // wave 0..11
    const int wl  = tid & 63;          // lane

    __shared__ float4   part0[2][12][48];   // rec ct0 partials (dbuf)
    __shared__ float4   part1[2][12][48];   // rec ct1 partials
    __shared__ float4   partF[2][12][48];   // FF partials
    __shared__ uint32_t ctm32_sh[48];       // cell-type bits per 32-neuron word

    // ---- cell-type bitmask via block-wide ballots (2 x 768) ----
    for (int r = 0; r < 2; ++r) {
        int c = ct[r * 768 + tid];
        uint64_t bal = __ballot(c != 0);
        if (wl == 0) {
            ctm32_sh[r * 24 + wv * 2]     = (uint32_t)bal;
            ctm32_sh[r * 24 + wv * 2 + 1] = (uint32_t)(bal >> 32);
        }
    }
    __syncthreads();

    // ---- owner-neuron constants (threads 0..191 own neuron m) ----
    const int m = j * 192 + ((tid < 192) ? tid : 0);
    const int   myct = ct[m];
    const float s0m  = sf[myct];
    const float s1m  = sf[2 + myct];
    const float sFm  = sfF[myct];
    const float lc   = (myct == 0) ? (1.0f / 200.0f) : (1.0f / 100.0f);
    const float refsteps = (myct == 0) ? 2.0f : 1.0f;
    const float ar0 = expf(-1.0f / 0.5f),  ad0 = expf(-1.0f / 2.0f);
    const float ar1 = expf(-1.0f / 2.0f),  ad1 = expf(-1.0f / 100.0f);
    const float ar2 = expf(-1.0f / 0.5f),  ad2 = expf(-1.0f / 5.0f);
    const float arF = expf(-1.0f / 0.5f),  adF = expf(-1.0f / 2.0f);

    float U = -65.0f, refc = 0.0f;
    float x0 = 0, g0 = 0, x1 = 0, g1 = 0, x2 = 0, g2 = 0, xF = 0, gF = 0;

    const int  btbase  = b * 256;
    const bool gl      = (wl < 48);                         // gather lane
    const uint32_t colbase = (uint32_t)(j * 192 + wl * 4);  // float offset in row

    // initial FF mask: wave wv ballots inputs wv*64..wv*64+63 of I[b,0,:]
    uint64_t fmask;
    {
        float iv = __builtin_nontemporal_load(
            &I[(uint32_t)btbase * 768u + (uint32_t)tid]);
        fmask = __ballot(iv > 0.5f);
    }

    for (int t = 0; t < 256; ++t) {
        // prefetch next-step input (consumed by the ballot after the gather)
        float ivn = 0.0f;
        if (t < 255)
            ivn = __builtin_nontemporal_load(
                &I[(uint32_t)(btbase + t + 1) * 768u + (uint32_t)tid]);

        float4 a0 = make_float4(0.f, 0.f, 0.f, 0.f);
        float4 a1 = a0, aF = a0;

        // ---- FF rows (always ready; fmask is this wave's own ballot) ----
        {
            uint64_t mm = fmask;   // wave-uniform
            while (mm) {
                const int bit = __builtin_ctzll(mm);
                mm &= mm - 1;
                const uint32_t row = (uint32_t)(wv * 64 + bit);
                if (gl) {
                    const float4 w = *(const float4*)(WF + row * 1536u + colbase);
                    aF.x += w.x; aF.y += w.y; aF.z += w.z; aF.w += w.w;
                }
            }
        }

        // ---- poll 4 rec words concurrently; gather each on arrival ----
        if (t > 0) {
            uint32_t ready = 0;
            const uint32_t pbase = (uint32_t)(btbase + t - 1) * 48u + (uint32_t)(wv * 4);
            do {
                uint64_t pv = 0;
                if (wl < 4)
                    pv = __hip_atomic_load(&recpub[pbase + (uint32_t)wl],
                                           __ATOMIC_RELAXED, __HIP_MEMORY_SCOPE_AGENT);
                const uint32_t plo = (uint32_t)pv;
                const uint32_t phi = (uint32_t)(pv >> 32);
                #pragma unroll
                for (int k = 0; k < 4; ++k) {
                    if (ready & (1u << k)) continue;
                    const uint32_t tg = __builtin_amdgcn_readlane(phi, k);
                    if (tg != (uint32_t)t) continue;      // not published yet
                    ready |= 1u << k;
                    uint32_t bits = __builtin_amdgcn_readlane(plo, k);
                    const uint32_t word = (uint32_t)(wv * 4 + k);
                    const uint32_t cm = ctm32_sh[word];
                    while (bits) {                         // wave-uniform row loop
                        const int bit = __builtin_ctz(bits);
                        bits &= bits - 1;
                        const uint32_t row = word * 32u + (uint32_t)bit;
                        if (gl) {
                            const float4 w = *(const float4*)(W + row * 1536u + colbase);
                            if ((cm >> bit) & 1u) {
                                a1.x += w.x; a1.y += w.y; a1.z += w.z; a1.w += w.w;
                            } else {
                                a0.x += w.x; a0.y += w.y; a0.z += w.z; a0.w += w.w;
                            }
                        }
                    }
                }
            } while (ready != 0xFu);
        }

        const int buf = t & 1;
        if (gl) {
            part0[buf][wv][wl] = a0;
            part1[buf][wv][wl] = a1;
            partF[buf][wv][wl] = aF;
        }
        fmask = __ballot(ivn > 0.5f);   // FF mask for step t+1 (per-wave register)
        __syncthreads();                // partials of ALL waves visible

        // ---- tail (threads 0..191): reduce, LIF, publish FIRST, store ----
        if (tid < 192) {
            const float* p0 = (const float*)&part0[buf][0][0];
            const float* p1 = (const float*)&part1[buf][0][0];
            const float* pF = (const float*)&partF[buf][0][0];
            float z0s = 0.f, z1s = 0.f, zFs = 0.f;
            #pragma unroll
            for (int k = 0; k < 12; ++k) {
                z0s += p0[k * 192 + tid];
                z1s += p1[k * 192 + tid];
                zFs += pF[k * 192 + tid];
            }
            z0s *= s0m; z1s *= s1m; zFs *= sFm;
            x0 = ar0 * x0 + z0s;  g0 = ad0 * g0 + x0;   // syn0 (pre ct0)
            x1 = ar1 * x1 + z0s;  g1 = ad1 * g1 + x1;   // syn1 (pre ct0, same z0)
            x2 = ar2 * x2 + z1s;  g2 = ad2 * g2 + x2;   // syn2 (pre ct1)
            xF = arF * xF + zFs;  gF = adF * gF + xF;   // feed-forward
            const float gtot = g0 + 0.5f * g1 + g2 + gF;   // gbar=[1,.5,1], FF 1
            const float gE   = -70.0f * g2;                // gbar*Erev=[0,0,-70], FF 0
            const float Isyn = gE - gtot * U;
            float Un = U + lc * (10.0f * (-65.0f - U) + Isyn);
            if (refc > 0.0f) Un = -65.0f;
            refc = fmaxf(refc - 1.0f, 0.0f);
            const bool s = (Un - (-50.0f)) >= 0.0f;
            // publish ASAP: waves 0..2 cover 64 consecutive neurons each;
            // lanes 0/32 store (tag<<32)|half — flag and data in one word.
            const uint64_t bal = __ballot(s);
            if (wl == 0 || wl == 32) {
                const uint32_t half = (wl == 0) ? (uint32_t)bal : (uint32_t)(bal >> 32);
                const uint32_t word = (uint32_t)(j * 6 + wv * 2) + (wl == 32 ? 1u : 0u);
                const uint32_t widx = (uint32_t)(btbase + t) * 48u + word;
                const uint64_t v = ((uint64_t)(uint32_t)(t + 1) << 32) | half;
                __hip_atomic_store(&recpub[widx], v, __ATOMIC_RELAXED,
                                   __HIP_MEMORY_SCOPE_AGENT);
            }
            const float Uo = s ? -65.0f : Un;
            refc = s ? refsteps : refc;
            U = Uo;
            const uint32_t oidx = (uint32_t)(btbase + t) * 1536u + (uint32_t)m;
            __builtin_nontemporal_store(s ? 1.0f : 0.0f, &out[oidx]);
            __builtin_nontemporal_store(Uo, &out[12582912u + oidx]);
        }
        // no second barrier: partials are double-buffered, and no wave can
        // reach step t+2's writes before all waves passed step t+1's barrier.
    }
}

extern "C" void kernel_launch(void* const* d_in, const int* in_sizes, int n_in,
                              void* d_out, int out_size, void* d_ws, size_t ws_size,
                              hipStream_t stream) {
    const float* I   = (const float*)d_in[0];   // input_spikes (32,256,768)
    const float* W   = (const float*)d_in[1];   // weights (1536,1536)
    const float* WF  = (const float*)d_in[2];   // weights_FF (768,1536)
    const float* sf  = (const float*)d_in[3];   // scaling_factors (2,2)
    const float* sfF = (const float*)d_in[4];   // scaling_factors_FF (1,2)
    const int*   ct  = (const int*)d_in[5];     // cell_type_indices (1536)
    // d_in[6] cell_type_indices_FF: all zeros, folded into sfF indexing.

    uint64_t* recpub = (uint64_t*)d_ws;   // 32*256*48*8 = 3,145,728 B

    snn_lif_kernel<<<dim3(256), dim3(768), 0, stream>>>(
        I, W, WF, sf, sfF, ct, (float*)d_out, recpub);
}